// Round 14
// baseline (128.350 us; speedup 1.0000x reference)
//
#include <hip/hip_runtime.h>

#define BB 4
#define NN 16384
#define MM 8192      // N/2
#define FD 64
#define TPB 256
#define BINS 128

// d_out float offsets
#define OUT0 0              // valid_pc   (4,8192,3)
#define OUT1 98304          // valid_feats(4,8192,64)
#define OUT2 2195456        // n_idx      (4,8192)
#define OUT3 2228224        // rnds       (1,16384)

// d_ws layout (bytes)
#define CAND_OFF    0
#define CAND_BYTES  ((size_t)BB * MM * 16)
#define SCAND_OFF   (CAND_OFF + CAND_BYTES)
#define SKIDX_OFF   (SCAND_OFF + CAND_BYTES)
#define IDX_BYTES   ((size_t)BB * MM * 4)
#define SQID_OFF    (SKIDX_OFF + IDX_BYTES)
#define QPACK_OFF   (SQID_OFF + IDX_BYTES)
#define BOUND_OFF   (QPACK_OFF + CAND_BYTES)
#define WWIN_OFF    (BOUND_OFF + IDX_BYTES)      // int2 x 256
#define META_OFF    (WWIN_OFF + 4096)
#define FIXED_BYTES (META_OFF + 16384)
// meta ints: khist 0(4x128), qhist 512, kcur 1024, qcur 1536, koff 2048(4x129), qoff 2564(4x129)

struct Partial { double m1, m2; };

// ---- HW-verified bit-exact pieces (r7/r10/r12/r13: absmax 0) ----
__device__ __forceinline__ float sumsq3_rn(float x, float y, float z) {
  return __fadd_rn(__fadd_rn(__fmul_rn(x, x), __fmul_rn(y, y)), __fmul_rn(z, z));
}
__device__ __forceinline__ float dist2_rn(float qx, float qy, float qz, float q2,
                                          float4 t) {
  float cross2 = __fmaf_rn(qz, t.z, __fmaf_rn(qy, t.y, __fmul_rn(qx, t.x)));
  return __fadd_rn(__fsub_rn(q2, cross2), t.w);
}
__device__ __forceinline__ double mkkey(float d2, int k) {
  return __hiloint2double(__float_as_int(d2), k);
}
#define KEY_INIT __hiloint2double(0x7F800000, 0x7FFFFFFF)

__device__ __forceinline__ int bin128(float v2x) {
  float f = floorf((v2x + 12.0f) * (BINS / 24.0f));
  f = fmaxf(0.0f, fminf((float)(BINS - 1), f));
  return (int)f;
}

// gather + cand prep + both histograms (r13-proven)
__global__ __launch_bounds__(256) void gather_kernel(
    const float* __restrict__ pc, const float* __restrict__ feats,
    const int* __restrict__ perm, float* __restrict__ out,
    float4* __restrict__ cand, int* __restrict__ meta) {
  int idx = blockIdx.x * 256 + threadIdx.x;
  const int F4_TOT = BB * MM * FD / 4;
  const int PTS    = BB * MM;
  if (idx < F4_TOT) {
    int f4 = idx & 15;
    int r  = (idx >> 4) & (MM - 1);
    int b  = idx >> 17;
    int vi = perm[r];
    const float4* src = (const float4*)(feats + ((b * NN + vi) << 6));
    float4* dst = (float4*)(out + OUT1) + idx;
    *dst = src[f4];
  } else if (idx < F4_TOT + PTS) {
    int k = idx - F4_TOT;
    int r = k & (MM - 1);
    int b = k >> 13;
    int vi = perm[r];
    const float* src = pc + (b * NN + vi) * 3;
    float px = src[0], py = src[1], pz = src[2];
    float* dst = out + OUT0 + k * 3;
    dst[0] = px; dst[1] = py; dst[2] = pz;
    cand[k] = make_float4(px + px, py + py, pz + pz, sumsq3_rn(px, py, pz));
    atomicAdd(&meta[0 + b * BINS + bin128(px + px)], 1);
  } else if (idx < F4_TOT + PTS + NN) {
    int k = idx - F4_TOT - PTS;
    out[OUT3 + k] = (float)perm[k];
  } else if (idx < F4_TOT + PTS + NN + BB * MM) {
    int qid = idx - F4_TOT - PTS - NN;
    int b = qid >> 13, j = qid & (MM - 1);
    int qi = perm[MM + j];
    float qx = pc[(b * NN + qi) * 3];
    atomicAdd(&meta[512 + b * BINS + bin128(qx + qx)], 1);
  }
}

__global__ void prefix_kernel(int* __restrict__ meta) {
  int t = threadIdx.x;
  if (t < 8) {
    const int* h = meta + (t < 4 ? t * BINS : 512 + (t - 4) * BINS);
    int* o = meta + (t < 4 ? 2048 + t * 129 : 2564 + (t - 4) * 129);
    int acc = 0;
    for (int i0 = 0; i0 < BINS; i0 += 16) {
      int v[16];
      #pragma unroll
      for (int i = 0; i < 16; ++i) v[i] = h[i0 + i];
      #pragma unroll
      for (int i = 0; i < 16; ++i) { o[i0 + i] = acc; acc += v[i]; }
    }
    o[BINS] = acc;
  }
}

// counting-sort scatter + qpack (query coords by sorted slot)
__global__ __launch_bounds__(256) void scatter_kernel(
    const float* __restrict__ pc, const int* __restrict__ perm,
    const float4* __restrict__ cand, int* __restrict__ meta,
    float4* __restrict__ scand, int* __restrict__ skidx,
    int* __restrict__ sqid, float4* __restrict__ qpack) {
  int idx = blockIdx.x * 256 + threadIdx.x;
  if (idx < BB * MM) {
    int b = idx >> 13;
    float4 cv = cand[idx];
    int bin = bin128(cv.x);
    int pos = meta[2048 + b * 129 + bin] + atomicAdd(&meta[1024 + b * BINS + bin], 1);
    int g = (b << 13) + pos;
    scand[g] = cv;
    skidx[g] = idx & (MM - 1);
  } else if (idx < 2 * BB * MM) {
    int qid = idx - BB * MM;
    int b = qid >> 13, j = qid & (MM - 1);
    int qi = perm[MM + j];
    const float* qp = pc + (b * NN + qi) * 3;
    float x = qp[0], y = qp[1], z = qp[2];
    int bin = bin128(x + x);
    int pos = meta[2564 + b * 129 + bin] + atomicAdd(&meta[1536 + b * BINS + bin], 1);
    int slot = (b << 13) + pos;
    sqid[slot] = j;
    qpack[slot] = make_float4(x, y, z, 0.0f);
  }
}

// bound: block = 128 sorted queries sharing ONE staged 1024-cand x-neighborhood.
// top-2 VALUES over a subset >= true m2 (same bit-exact rounded metric).
__global__ __launch_bounds__(256) void bound_kernel(
    const float4* __restrict__ qpack, const float4* __restrict__ scand,
    const int* __restrict__ meta, float* __restrict__ bound2) {
  #pragma clang fp contract(off)
  int b = blockIdx.x >> 6;                // 256 blocks, 64 per batch
  int qs = (blockIdx.x & 63) * 128;
  int bbase = b << 13;
  float qmx = qpack[bbase + qs + 64].x;   // block median query (broadcast load)
  const int* koff = meta + 2048 + b * 129;
  int ck = koff[bin128(qmx + qmx)];
  int lo = min(max(ck - 512, 0), MM - 1024);

  __shared__ float4 ctile[1024];          // 16 KB
  __shared__ float pm1[2][2][64], pm2[2][2][64];
  int t = threadIdx.x;
  #pragma unroll
  for (int i = 0; i < 4; ++i) ctile[t + i * 256] = scand[bbase + lo + t + i * 256];
  __syncthreads();

  int wid = t >> 6, lane = t & 63;
  int g = wid >> 1, h = wid & 1;          // query group / candidate half
  float4 qp = qpack[bbase + qs + g * 64 + lane];
  float q2 = sumsq3_rn(qp.x, qp.y, qp.z);
  float m1 = 3.4e38f, m2 = 3.4e38f;
  #pragma unroll 4
  for (int k = h * 512; k < h * 512 + 512; ++k) {
    float d2 = dist2_rn(qp.x, qp.y, qp.z, q2, ctile[k]);
    m2 = __builtin_amdgcn_fmed3f(d2, m1, m2);
    m1 = fminf(d2, m1);
  }
  pm1[g][h][lane] = m1; pm2[g][h][lane] = m2;
  __syncthreads();
  if (t < 128) {
    int g2 = t >> 6, l2 = t & 63;
    float a1 = pm1[g2][0][l2], a2 = pm2[g2][0][l2];
    float b1 = pm1[g2][1][l2], b2 = pm2[g2][1][l2];
    bound2[bbase + qs + t] = fminf(fmaxf(a1, b1), fminf(a2, b2));
  }
}

// wwin: per 128-query wave-group, window [plo,phi) (r13's HW-validated formula)
__global__ __launch_bounds__(256) void wwin_kernel(
    const float4* __restrict__ qpack, const float* __restrict__ bound2,
    const int* __restrict__ meta, int2* __restrict__ wwin) {
  #pragma clang fp contract(off)
  int wid = threadIdx.x >> 6, lane = threadIdx.x & 63;
  int wg = blockIdx.x * 4 + wid;          // 0..255
  int b = wg >> 6;
  int s0 = (b << 13) + (wg & 63) * 128;
  float lo = 3.4e38f, hi = -3.4e38f;
  #pragma unroll
  for (int s = 0; s < 2; ++s) {
    float4 qp = qpack[s0 + lane + s * 64];
    float bf = bound2[s0 + lane + s * 64];
    float r2 = 2.0f * sqrtf(bf + 1e-3f) * 1.0001f;   // slack >> rounding err
    lo = fminf(lo, (qp.x + qp.x) - r2);
    hi = fmaxf(hi, (qp.x + qp.x) + r2);
  }
  #pragma unroll
  for (int m = 1; m < 64; m <<= 1) {
    lo = fminf(lo, __shfl_xor(lo, m));
    hi = fmaxf(hi, __shfl_xor(hi, m));
  }
  if (lane == 0) {
    const int* koff = meta + 2048 + b * 129;
    wwin[wg] = make_int2(koff[bin128(lo)], koff[bin128(hi) + 1]);
  }
}

// knn: wave = 128 x-sorted queries; per-wave 64-cand LDS tiles (no barriers);
// inner loop identical to r10's proven f64 packed-key update.
__global__ __launch_bounds__(256) void knn_kernel(
    const float4* __restrict__ qpack, const int* __restrict__ sqid,
    const float4* __restrict__ scand, const int* __restrict__ skidx,
    const int2* __restrict__ wwin,
    Partial* __restrict__ part, float* __restrict__ out, int nchunk) {
  #pragma clang fp contract(off)
  int c   = blockIdx.x % nchunk;
  int wgq = blockIdx.x / nchunk;          // 0..63
  int wid = threadIdx.x >> 6, lane = threadIdx.x & 63;
  int wg = wgq * 4 + wid;                 // 0..255
  int b  = wg >> 6;
  int bbase = b << 13;
  int s0 = bbase + (wg & 63) * 128;

  float qx[2], qy[2], qz[2], q2[2];
  int qorig[2];
  #pragma unroll
  for (int s = 0; s < 2; ++s) {
    int slot = s0 + lane + s * 64;
    float4 qp = qpack[slot];
    qx[s] = qp.x; qy[s] = qp.y; qz[s] = qp.z;
    q2[s] = sumsq3_rn(qp.x, qp.y, qp.z);
    qorig[s] = bbase + sqid[slot];
  }
  int2 win = wwin[wg];
  int chunklen = (win.y - win.x + nchunk - 1) / nchunk;
  int start = win.x + c * chunklen;
  int end = min(start + chunklen, win.y);

  double m1[2] = {KEY_INIT, KEY_INIT}, m2[2] = {KEY_INIT, KEY_INIT};
  __shared__ float4 ct[4][64];
  __shared__ int    it[4][64];

  for (int t0 = start; t0 < end; t0 += 64) {
    int pos = bbase + min(t0 + lane, win.y - 1);
    ct[wid][lane] = scand[pos];           // coalesced 1KB/wave
    it[wid][lane] = skidx[pos];
    int kmax = min(64, end - t0);
    #pragma unroll 4
    for (int k = 0; k < kmax; ++k) {
      float4 t = ct[wid][k];              // wave-broadcast LDS read
      int ki = it[wid][k];
      #pragma unroll
      for (int s = 0; s < 2; ++s) {
        float d2 = dist2_rn(qx[s], qy[s], qz[s], q2[s], t);
        double key = mkkey(d2, ki);
        m2[s] = fmin(fmax(key, m1[s]), m2[s]);
        m1[s] = fmin(key, m1[s]);
      }
    }
  }

  #pragma unroll
  for (int s = 0; s < 2; ++s) {
    if (part != nullptr) {
      Partial pr; pr.m1 = m1[s]; pr.m2 = m2[s];
      part[qorig[s] * nchunk + c] = pr;
    } else {
      out[OUT2 + qorig[s]] = (float)__double2loint(m2[s]);
    }
  }
}

__global__ __launch_bounds__(256) void knn_merge_kernel(
    const Partial* __restrict__ part, float* __restrict__ out, int nchunk) {
  int q = blockIdx.x * 256 + threadIdx.x;
  double m1 = KEY_INIT, m2 = KEY_INIT;
  for (int c = 0; c < nchunk; ++c) {
    Partial p = part[q * nchunk + c];
    m2 = fmin(fmax(p.m1, m1), m2);
    m1 = fmin(p.m1, m1);
    m2 = fmin(fmax(p.m2, m1), m2);
    m1 = fmin(p.m2, m1);
  }
  out[OUT2 + q] = (float)__double2loint(m2);
}

extern "C" void kernel_launch(void* const* d_in, const int* in_sizes, int n_in,
                              void* d_out, int out_size, void* d_ws, size_t ws_size,
                              hipStream_t stream) {
  const float* pc    = (const float*)d_in[0];
  const float* feats = (const float*)d_in[1];
  const int*   perm  = (const int*)d_in[2];
  float* out = (float*)d_out;

  char* ws = (char*)d_ws;
  float4* cand   = (float4*)(ws + CAND_OFF);
  float4* scand  = (float4*)(ws + SCAND_OFF);
  int*    skidx  = (int*)(ws + SKIDX_OFF);
  int*    sqid   = (int*)(ws + SQID_OFF);
  float4* qpack  = (float4*)(ws + QPACK_OFF);
  float*  bound2 = (float*)(ws + BOUND_OFF);
  int2*   wwin   = (int2*)(ws + WWIN_OFF);
  int*    meta   = (int*)(ws + META_OFF);
  char*   rest   = ws + FIXED_BYTES;
  size_t  avail  = ws_size > FIXED_BYTES ? ws_size - FIXED_BYTES : 0;

  hipMemsetAsync(meta, 0, 2048 * sizeof(int), stream);

  gather_kernel<<<2368, 256, 0, stream>>>(pc, feats, perm, out, cand, meta);
  prefix_kernel<<<1, 64, 0, stream>>>(meta);
  scatter_kernel<<<256, 256, 0, stream>>>(pc, perm, cand, meta, scand, skidx,
                                          sqid, qpack);
  bound_kernel<<<256, 256, 0, stream>>>(qpack, scand, meta, bound2);
  wwin_kernel<<<64, 256, 0, stream>>>(qpack, bound2, meta, wwin);

  int nchunk = 1;
  if      (avail >= (size_t)BB * MM * 8 * sizeof(Partial)) nchunk = 8;   // 4.2 MB
  else if (avail >= (size_t)BB * MM * 4 * sizeof(Partial)) nchunk = 4;
  else if (avail >= (size_t)BB * MM * 2 * sizeof(Partial)) nchunk = 2;

  if (nchunk > 1) {
    Partial* part = (Partial*)rest;
    knn_kernel<<<64 * nchunk, TPB, 0, stream>>>(qpack, sqid, scand, skidx, wwin,
                                                part, out, nchunk);
    knn_merge_kernel<<<BB * MM / 256, 256, 0, stream>>>(part, out, nchunk);
  } else {
    knn_kernel<<<64, TPB, 0, stream>>>(qpack, sqid, scand, skidx, wwin,
                                       nullptr, out, 1);
  }
}

// Round 15
// 77.384 us; speedup vs baseline: 1.6586x; 1.6586x over previous
//
#include <hip/hip_runtime.h>

#define BB 4
#define NN 16384
#define MM 8192      // N/2
#define FD 64
#define CHUNK 256    // LDS tile (1 cand per thread)
#define TPB 256
#define QPB 512      // queries per query-block (QPT=2)

// d_out float offsets
#define OUT0 0              // valid_pc   (4,8192,3)
#define OUT1 98304          // valid_feats(4,8192,64)
#define OUT2 2195456        // n_idx      (4,8192)
#define OUT3 2228224        // rnds       (1,16384)

// d_ws layout
#define CAND_OFF   0
#define CAND_BYTES ((size_t)BB * MM * 16)                 // 512 KB
#define CPAIR_OFF  (CAND_OFF + CAND_BYTES)
#define CPAIR_BYTES ((size_t)BB * MM * 8)                 // 256 KB
#define PART_OFF   (CPAIR_OFF + CPAIR_BYTES)

// ---- HW-verified bit-exact pieces (r7/r10: absmax 0) ----
__device__ __forceinline__ float sumsq3_rn(float x, float y, float z) {
  return __fadd_rn(__fadd_rn(__fmul_rn(x, x), __fmul_rn(y, y)), __fmul_rn(z, z));
}
__device__ __forceinline__ float dist2_rn(float qx, float qy, float qz, float q2,
                                          float4 t) {
  float cross2 = __fmaf_rn(qz, t.z, __fmaf_rn(qy, t.y, __fmul_rn(qx, t.x)));
  return __fadd_rn(__fsub_rn(q2, cross2), t.w);
}
__device__ __forceinline__ double mkkey(float d2, int k) {
  return __hiloint2double(__float_as_int(d2), k);
}
#define KEY_INIT __hiloint2double(0x7F800000, 0x7FFFFFFF)

// gather + cand prep (r9-proven)
__global__ __launch_bounds__(256) void gather_kernel(
    const float* __restrict__ pc, const float* __restrict__ feats,
    const int* __restrict__ perm, float* __restrict__ out,
    float4* __restrict__ cand) {
  int idx = blockIdx.x * 256 + threadIdx.x;
  const int F4_TOT = BB * MM * FD / 4;
  const int PTS    = BB * MM;
  if (idx < F4_TOT) {
    int f4 = idx & 15;
    int r  = (idx >> 4) & (MM - 1);
    int b  = idx >> 17;
    int vi = perm[r];
    const float4* src = (const float4*)(feats + ((b * NN + vi) << 6));
    float4* dst = (float4*)(out + OUT1) + idx;
    *dst = src[f4];
  } else if (idx < F4_TOT + PTS) {
    int k = idx - F4_TOT;
    int r = k & (MM - 1);
    int b = k >> 13;
    int vi = perm[r];
    const float* src = pc + (b * NN + vi) * 3;
    float px = src[0], py = src[1], pz = src[2];
    float* dst = out + OUT0 + k * 3;
    dst[0] = px; dst[1] = py; dst[2] = pz;
    cand[k] = make_float4(px + px, py + py, pz + pz, sumsq3_rn(px, py, pz));
  } else if (idx < F4_TOT + PTS + NN) {
    int k = idx - F4_TOT - PTS;
    out[OUT3 + k] = (float)perm[k];
  }
}

// Main pass: top-2 VALUES per (query, chunk). 2 f32 ops/pair update (r7-proven
// med3/min recurrence), no indices, no f64 — the minimal VALU loop.
__global__ __launch_bounds__(256) void knn_val_kernel(
    const float* __restrict__ pc, const int* __restrict__ perm,
    const float4* __restrict__ cand, float2* __restrict__ part, int nchunk) {
  #pragma clang fp contract(off)
  int c  = blockIdx.x % nchunk;
  int qb = blockIdx.x / nchunk;       // 0..63
  int q0 = qb * QPB + threadIdx.x;
  int b  = qb >> 4;                   // uniform

  float qx[2], qy[2], qz[2], q2[2], m1[2], m2[2];
  #pragma unroll
  for (int s = 0; s < 2; ++s) {
    int q = q0 + s * TPB;
    int j = q & (MM - 1);
    int qi = perm[MM + j];
    const float* qp = pc + (b * NN + qi) * 3;
    qx[s] = qp[0]; qy[s] = qp[1]; qz[s] = qp[2];
    q2[s] = sumsq3_rn(qx[s], qy[s], qz[s]);
    m1[s] = 3.4e38f; m2[s] = 3.4e38f;
  }

  __shared__ float4 tile[CHUNK];      // 4 KB

  int span = MM / nchunk;
  int begin = c * span, end = begin + span;

  for (int t0 = begin; t0 < end; t0 += CHUNK) {
    __syncthreads();
    tile[threadIdx.x] = cand[b * MM + t0 + threadIdx.x];
    __syncthreads();
    #pragma unroll 8
    for (int k = 0; k < CHUNK; ++k) {
      float4 t = tile[k];
      #pragma unroll
      for (int s = 0; s < 2; ++s) {
        float d2 = dist2_rn(qx[s], qy[s], qz[s], q2[s], t);
        m2[s] = __builtin_amdgcn_fmed3f(d2, m1[s], m2[s]);
        m1[s] = fminf(d2, m1[s]);
      }
    }
  }

  #pragma unroll
  for (int s = 0; s < 2; ++s) {
    int q = q0 + s * TPB;
    part[q * nchunk + c] = make_float2(m1[s], m2[s]);
  }
}

// Merge: per query, pack (value, chunk) as f64 keys (chunk order == index-range
// order, so earlier-chunk tie-wins == lower-index tie-wins, matching stable
// top_k — same key argument HW-verified in r10). Emits the two chunks that
// provably contain the stable top-2 candidates.
__global__ __launch_bounds__(256) void merge_kernel(
    const float2* __restrict__ part, int2* __restrict__ cpair, int nchunk) {
  int q = blockIdx.x * 256 + threadIdx.x;
  double k1 = KEY_INIT, k2 = KEY_INIT;
  for (int c = 0; c < nchunk; ++c) {
    float2 p = part[q * nchunk + c];
    double a = mkkey(p.x, c);
    double d = mkkey(p.y, c);
    k2 = fmin(fmax(a, k1), k2);
    k1 = fmin(a, k1);
    k2 = fmin(fmax(d, k1), k2);
    k1 = fmin(d, k1);
  }
  cpair[q] = make_int2(__double2loint(k1), __double2loint(k2));
}

// Recovery: one wave per query; rescan chunks c1 (and c2 if distinct) with the
// exact f64 (d2,index) key machine (r10-proven), lane-parallel + shfl top-2.
__global__ __launch_bounds__(256) void recover_kernel(
    const float* __restrict__ pc, const int* __restrict__ perm,
    const float4* __restrict__ cand, const int2* __restrict__ cpair,
    float* __restrict__ out, int nchunk) {
  #pragma clang fp contract(off)
  int wid = threadIdx.x >> 6, lane = threadIdx.x & 63;
  int q = blockIdx.x * 4 + wid;       // 0..B*M-1
  int b = q >> 13, j = q & (MM - 1);
  int qi = perm[MM + j];
  const float* qp = pc + (b * NN + qi) * 3;   // wave-uniform loads
  float qx = qp[0], qy = qp[1], qz = qp[2];
  float q2 = sumsq3_rn(qx, qy, qz);
  int2 cp = cpair[q];
  int clen = MM / nchunk;
  const float4* cb = cand + (b << 13);

  double m1 = KEY_INIT, m2 = KEY_INIT;
  #pragma unroll
  for (int pass = 0; pass < 2; ++pass) {
    int c = pass == 0 ? cp.x : cp.y;
    if (pass == 1 && cp.y == cp.x) break;   // no double-insertion
    int base = c * clen;
    for (int i = lane; i < clen; i += 64) { // coalesced
      float4 t = cb[base + i];
      float d2 = dist2_rn(qx, qy, qz, q2, t);
      double key = mkkey(d2, base + i);
      m2 = fmin(fmax(key, m1), m2);
      m1 = fmin(key, m1);
    }
  }
  #pragma unroll
  for (int mask = 1; mask < 64; mask <<= 1) {
    double o1 = __shfl_xor(m1, mask);
    double o2 = __shfl_xor(m2, mask);
    double n1 = fmin(m1, o1);
    double n2 = fmin(fmax(m1, o1), fmin(m2, o2));
    m1 = n1; m2 = n2;
  }
  if (lane == 0) out[OUT2 + q] = (float)__double2loint(m2);
}

extern "C" void kernel_launch(void* const* d_in, const int* in_sizes, int n_in,
                              void* d_out, int out_size, void* d_ws, size_t ws_size,
                              hipStream_t stream) {
  const float* pc    = (const float*)d_in[0];
  const float* feats = (const float*)d_in[1];
  const int*   perm  = (const int*)d_in[2];
  float* out = (float*)d_out;

  char* ws = (char*)d_ws;
  float4* cand  = (float4*)(ws + CAND_OFF);
  int2*   cpair = (int2*)(ws + CPAIR_OFF);
  float2* part  = (float2*)(ws + PART_OFF);
  size_t  avail = ws_size > PART_OFF ? ws_size - PART_OFF : 0;

  gather_kernel<<<2240, 256, 0, stream>>>(pc, feats, perm, out, cand);

  // nchunk: 32 -> 2048 blocks (8/CU, best measured shape), part = 8.4 MB
  int nchunk = 8;
  if      (avail >= (size_t)BB * MM * 32 * sizeof(float2)) nchunk = 32;
  else if (avail >= (size_t)BB * MM * 16 * sizeof(float2)) nchunk = 16;

  knn_val_kernel<<<64 * nchunk, TPB, 0, stream>>>(pc, perm, cand, part, nchunk);
  merge_kernel<<<BB * MM / 256, 256, 0, stream>>>(part, cpair, nchunk);
  recover_kernel<<<BB * MM / 4, 256, 0, stream>>>(pc, perm, cand, cpair, out, nchunk);
}